// Round 1
// baseline (812.269 us; speedup 1.0000x reference)
//
#include <hip/hip_runtime.h>

#define SEQ   512
#define BATCH 128
#define FEAT  1024
#define EMBED 1024

// Tile config: 128x128 output tile, BK=64, 256 threads (4 waves, 2x2),
// each wave computes 64x64 via 4x4 fragments of mfma_f32_16x16x32_bf16.
constexpr int BM = 128, BN = 128, BK = 64;

typedef __attribute__((ext_vector_type(8))) short bf16x8;
typedef __attribute__((ext_vector_type(4))) float f32x4;

// f32 -> bf16 round-to-nearest-even (finite inputs)
__device__ __forceinline__ unsigned short f2bf(float x) {
  unsigned u = __float_as_uint(x);
  u += 0x7fffu + ((u >> 16) & 1u);
  return (unsigned short)(u >> 16);
}
__device__ __forceinline__ unsigned pk2(float a, float b) {
  return (unsigned)f2bf(a) | ((unsigned)f2bf(b) << 16);
}

__global__ __launch_bounds__(256, 2) void grouped_proj_kernel(
    const float* __restrict__ feat,   // [S,B,F]
    const float* __restrict__ Wt,     // [L,E,F]
    const float* __restrict__ bias,   // [L,E]
    const int*   __restrict__ toks,   // [B]
    float*       __restrict__ out)    // [S,B,E]
{
  // Fragment-sequential LDS layout: slot a16 = (kk*8 + mfrag)*64 + lane,
  // 16B per slot (8 bf16 = one MFMA operand register set). Reads are
  // lane-sequential -> bank-conflict-free ds_read_b128.
  __shared__ uint4 As[1024];  // 16 KiB
  __shared__ uint4 Bs[1024];  // 16 KiB

  const int et  = blockIdx.x;       // E tile 0..7   (fastest: co-resident blocks share feat tile)
  const int st  = blockIdx.y;       // S tile 0..3
  const int b   = blockIdx.z;       // batch 0..127
  const int tok = toks[b];
  const int s0  = st * BM;
  const int e0  = et * BN;

  const int tid  = threadIdx.x;
  const int lane = tid & 63;
  const int wv   = tid >> 6;
  const int wr   = wv >> 1;         // wave row (M half)
  const int wc   = wv & 1;          // wave col (N half)

  f32x4 acc[4][4] = {};

  const float* Ab = feat + ((size_t)s0 * BATCH + b) * FEAT;          // row stride BATCH*FEAT
  const float* Bb = Wt + ((size_t)tok * EMBED + e0) * FEAT;          // row stride FEAT

  for (int k0 = 0; k0 < FEAT; k0 += BK) {
    __syncthreads();
    // Stage A (feat) and B (W) tiles: 128 rows x 64 k each, converted to bf16.
    // chunk c = kg*128 + row; thread handles one 8-element k-group per matrix.
    // 16 consecutive threads -> 16 consecutive rows => write bank-quad = row&7
    // covers all 8 quads -> conflict-free ds_writes.
#pragma unroll
    for (int it = 0; it < 4; ++it) {
      const int c   = it * 256 + tid;
      const int row = c & 127;
      const int kg  = c >> 7;                       // 0..7 (8 bf16 each)
      const int dl  = (row & 15) + (kg & 3) * 16;   // dest lane within fragment
      const int a16 = ((kg >> 2) * 8 + (row >> 4)) * 64 + dl;

      const float* ga = Ab + (size_t)row * (BATCH * FEAT) + (k0 + kg * 8);
      float4 alo = *(const float4*)ga;
      float4 ahi = *(const float4*)(ga + 4);
      uint4 av;
      av.x = pk2(alo.x, alo.y); av.y = pk2(alo.z, alo.w);
      av.z = pk2(ahi.x, ahi.y); av.w = pk2(ahi.z, ahi.w);
      As[a16] = av;

      const float* gb = Bb + (size_t)row * FEAT + (k0 + kg * 8);
      float4 blo = *(const float4*)gb;
      float4 bhi = *(const float4*)(gb + 4);
      uint4 bv;
      bv.x = pk2(blo.x, blo.y); bv.y = pk2(blo.z, blo.w);
      bv.z = pk2(bhi.x, bhi.y); bv.w = pk2(bhi.z, bhi.w);
      Bs[a16] = bv;
    }
    __syncthreads();

#pragma unroll
    for (int kk = 0; kk < 2; ++kk) {
      bf16x8 af[4], bfr[4];
#pragma unroll
      for (int mi = 0; mi < 4; ++mi)
        af[mi] = ((const bf16x8*)As)[(kk * 8 + wr * 4 + mi) * 64 + lane];
#pragma unroll
      for (int ni = 0; ni < 4; ++ni)
        bfr[ni] = ((const bf16x8*)Bs)[(kk * 8 + wc * 4 + ni) * 64 + lane];
#pragma unroll
      for (int mi = 0; mi < 4; ++mi)
#pragma unroll
        for (int ni = 0; ni < 4; ++ni)
          acc[mi][ni] = __builtin_amdgcn_mfma_f32_16x16x32_bf16(
              af[mi], bfr[ni], acc[mi][ni], 0, 0, 0);
    }
  }

  // Epilogue: C/D layout col = lane&15 (-> e), row = (lane>>4)*4 + j (-> s).
  const int col = lane & 15;
  const int r0  = (lane >> 4) * 4;
#pragma unroll
  for (int ni = 0; ni < 4; ++ni) {
    const int e = e0 + wc * 64 + ni * 16 + col;
    const float bvv = bias[tok * EMBED + e];
#pragma unroll
    for (int mi = 0; mi < 4; ++mi) {
#pragma unroll
      for (int j = 0; j < 4; ++j) {
        const int s = s0 + wr * 64 + mi * 16 + r0 + j;
        out[((size_t)s * BATCH + b) * EMBED + e] = acc[mi][ni][j] + bvv;
      }
    }
  }
}

extern "C" void kernel_launch(void* const* d_in, const int* in_sizes, int n_in,
                              void* d_out, int out_size, void* d_ws, size_t ws_size,
                              hipStream_t stream) {
  const float* feat = (const float*)d_in[0];
  const float* W    = (const float*)d_in[1];
  const float* bias = (const float*)d_in[2];
  const int*   toks = (const int*)d_in[3];
  float* out = (float*)d_out;

  dim3 grid(EMBED / BN, SEQ / BM, BATCH);   // (8, 4, 128)
  dim3 block(256);
  grouped_proj_kernel<<<grid, block, 0, stream>>>(feat, W, bias, toks, out);
}

// Round 2
// 492.936 us; speedup vs baseline: 1.6478x; 1.6478x over previous
//
#include <hip/hip_runtime.h>
#include <hip/hip_bf16.h>

#define SEQ   512
#define BATCH 128
#define FEAT  1024
#define EMBED 1024

// 128x128 tile, BK=64, 256 threads (4 waves 2x2), wave = 64x64 via 4x4
// fragments of mfma_f32_16x16x32_bf16. M dimension = flattened (s,b) rows of
// feat ([S*B, F] row-major), permuted so each language's rows are contiguous
// (segment length 512*c_l, always a multiple of 128 -> no tile straddle).
constexpr int BM = 128, BN = 128, BK = 64;

typedef __attribute__((ext_vector_type(8))) short bf16x8;
typedef __attribute__((ext_vector_type(4))) float f32x4;

__device__ __forceinline__ unsigned pk2(float a, float b) {
  float2 f; f.x = a; f.y = b;
  __hip_bfloat162 h = __float22bfloat162_rn(f);   // v_cvt_pk_bf16_f32
  union { __hip_bfloat162 h2; unsigned u; } cv;
  cv.h2 = h;
  return cv.u;
}

__global__ __launch_bounds__(256, 2) void grouped_proj_kernel(
    const float* __restrict__ feat,   // [S*B, F] row-major
    const float* __restrict__ Wt,     // [L, E, F]
    const float* __restrict__ bias,   // [L, E]
    const int*   __restrict__ toks,   // [B]
    float*       __restrict__ out)    // [S*B, E]
{
  __shared__ uint4 As[1024];               // 16 KiB bf16 128x64 (fragment slots)
  __shared__ uint4 Bs[1024];               // 16 KiB
  __shared__ int tokarr[128];
  __shared__ unsigned long long ballots[2][8];
  __shared__ int perm[128];
  __shared__ int rowsrc[128];

  const int tid  = threadIdx.x;
  const int lane = tid & 63;
  const int wv   = tid >> 6;
  const int wr   = wv >> 1;
  const int wc   = wv & 1;

  // XCD-aware mapping: the 8 et-siblings of one mt are ADJACENT in one XCD's
  // queue (assumes xcd = bid%8 round-robin) -> A-tile (512 KB) L2 reuse x8.
  const int bid = blockIdx.x;
  const int xcd = bid & 7;
  const int sq  = bid >> 3;
  const int et  = sq & 7;
  const int mt  = (sq >> 3) * 8 + xcd;
  const int m0  = mt * BM;
  const int e0  = et * BN;

  // ---- bucket setup: histogram + rank via per-wave ballots ----
  if (tid < 128) tokarr[tid] = toks[tid];
  __syncthreads();
  if (tid < 128) {
    int myt = tokarr[tid];
#pragma unroll
    for (int l = 0; l < 8; ++l) {
      unsigned long long bl = __ballot(myt == l);
      if (lane == 0) ballots[wv][l] = bl;
    }
  }
  __syncthreads();

  int lsel = 0, base = 0, csel = 1, boff_sel = 0;
  {
    int cum = 0, boff = 0;
#pragma unroll
    for (int l = 0; l < 8; ++l) {
      int c = __popcll(ballots[0][l]) + __popcll(ballots[1][l]);
      int seg = c << 9;                       // 512 * c_l rows
      bool in = (m0 >= cum) && (m0 < cum + seg);
      if (in) { lsel = l; base = cum; csel = c; boff_sel = boff; }
      cum += seg; boff += c;
    }
  }

  if (tid < 128) {
    int myt = tokarr[tid];
    unsigned long long ltm = (1ull << lane) - 1ull;
    int rank = (wv == 0) ? __popcll(ballots[0][myt] & ltm)
                         : __popcll(ballots[0][myt]) + __popcll(ballots[1][myt] & ltm);
    int boff2 = 0;
#pragma unroll
    for (int l = 0; l < 8; ++l) {
      int c = __popcll(ballots[0][l]) + __popcll(ballots[1][l]);
      boff2 += (l < myt) ? c : 0;
    }
    perm[boff2 + rank] = tid;
  }
  __syncthreads();
  if (tid < 128) {
    int local = m0 - base + tid;              // row within language segment
    int s = local / csel;
    int j = local - s * csel;
    rowsrc[tid] = s * BATCH + perm[boff_sel + j];
  }
  __syncthreads();

  // ---- staging assignment: chunk c = it*256+tid; kg = c&7 (8 floats, k-contig
  // across 8 lanes -> 256 B/row coalesced), row = c>>3. LDS slot XOR-swizzled
  // so each 16-lane write phase covers all bank-quads 2x (free). ----
  int slot_i[4];
  const float* aptr[4];
  const float* bptr[4];
#pragma unroll
  for (int it = 0; it < 4; ++it) {
    int c    = it * 256 + tid;
    int kg   = c & 7;
    int row  = c >> 3;
    int ksub = kg & 3;
    int kk   = kg >> 2;
    int frag = row >> 4;
    slot_i[it] = (kk * 8 + frag) * 64 + ((row & 15) ^ (ksub << 1) ^ kk) + ksub * 16;
    aptr[it] = feat + (size_t)rowsrc[row] * FEAT + kg * 8;
    bptr[it] = Wt + ((size_t)lsel * EMBED + e0 + row) * FEAT + kg * 8;
  }

  f32x4 acc[4][4] = {};

  for (int k0 = 0; k0 < FEAT; k0 += BK) {
    __syncthreads();
#pragma unroll
    for (int it = 0; it < 4; ++it) {
      float4 alo = *(const float4*)(aptr[it] + k0);
      float4 ahi = *(const float4*)(aptr[it] + k0 + 4);
      uint4 av;
      av.x = pk2(alo.x, alo.y); av.y = pk2(alo.z, alo.w);
      av.z = pk2(ahi.x, ahi.y); av.w = pk2(ahi.z, ahi.w);
      As[slot_i[it]] = av;
      float4 blo = *(const float4*)(bptr[it] + k0);
      float4 bhi = *(const float4*)(bptr[it] + k0 + 4);
      uint4 bv;
      bv.x = pk2(blo.x, blo.y); bv.y = pk2(blo.z, blo.w);
      bv.z = pk2(bhi.x, bhi.y); bv.w = pk2(bhi.z, bhi.w);
      Bs[slot_i[it]] = bv;
    }
    __syncthreads();

#pragma unroll
    for (int kk = 0; kk < 2; ++kk) {
      const int ksr = lane >> 4;
      const int sw  = ((lane & 15) ^ (ksr << 1) ^ kk) + ksr * 16;
      bf16x8 af[4], bfr[4];
#pragma unroll
      for (int mi = 0; mi < 4; ++mi)
        af[mi] = ((const bf16x8*)As)[(kk * 8 + wr * 4 + mi) * 64 + sw];
#pragma unroll
      for (int ni = 0; ni < 4; ++ni)
        bfr[ni] = ((const bf16x8*)Bs)[(kk * 8 + wc * 4 + ni) * 64 + sw];
#pragma unroll
      for (int mi = 0; mi < 4; ++mi)
#pragma unroll
        for (int ni = 0; ni < 4; ++ni)
          acc[mi][ni] = __builtin_amdgcn_mfma_f32_16x16x32_bf16(
              af[mi], bfr[ni], acc[mi][ni], 0, 0, 0);
    }
  }

  // ---- epilogue: C/D layout col = lane&15 (-> e), row = (lane>>4)*4+j (-> m) ----
  const int col = lane & 15;
  const int r0  = (lane >> 4) * 4;
  float bvv[4];
#pragma unroll
  for (int ni = 0; ni < 4; ++ni)
    bvv[ni] = bias[lsel * EMBED + e0 + wc * 64 + ni * 16 + col];
#pragma unroll
  for (int mi = 0; mi < 4; ++mi) {
#pragma unroll
    for (int j = 0; j < 4; ++j) {
      const size_t ro = (size_t)rowsrc[wr * 64 + mi * 16 + r0 + j] * EMBED;
#pragma unroll
      for (int ni = 0; ni < 4; ++ni)
        out[ro + e0 + wc * 64 + ni * 16 + col] = acc[mi][ni][j] + bvv[ni];
    }
  }
}

extern "C" void kernel_launch(void* const* d_in, const int* in_sizes, int n_in,
                              void* d_out, int out_size, void* d_ws, size_t ws_size,
                              hipStream_t stream) {
  const float* feat = (const float*)d_in[0];
  const float* W    = (const float*)d_in[1];
  const float* bias = (const float*)d_in[2];
  const int*   toks = (const int*)d_in[3];
  float* out = (float*)d_out;

  dim3 grid((SEQ * BATCH / BM) * (EMBED / BN));   // 512 * 8 = 4096
  dim3 block(256);
  grouped_proj_kernel<<<grid, block, 0, stream>>>(feat, W, bias, toks, out);
}

// Round 3
// 307.773 us; speedup vs baseline: 2.6392x; 1.6016x over previous
//
#include <hip/hip_runtime.h>
#include <hip/hip_bf16.h>

#define SEQ   512
#define BATCH 128
#define FEAT  1024
#define EMBED 1024
#define NLANG 8

constexpr int BM = 128, BN = 128, BK = 64;

typedef __attribute__((ext_vector_type(8))) short bf16x8;
typedef __attribute__((ext_vector_type(4))) float f32x4;

__device__ __forceinline__ unsigned pk2(float a, float b) {
  float2 f; f.x = a; f.y = b;
  __hip_bfloat162 h = __float22bfloat162_rn(f);   // v_cvt_pk_bf16_f32
  union { __hip_bfloat162 h2; unsigned u; } cv;
  cv.h2 = h;
  return cv.u;
}

// async global->LDS, 16B per lane. LDS dest must be wave-uniform base (HW adds
// lane*16); global src is per-lane.
__device__ __forceinline__ void gld16(const void* g, void* l) {
  __builtin_amdgcn_global_load_lds(
      (const __attribute__((address_space(1))) void*)g,
      (__attribute__((address_space(3))) void*)l, 16, 0, 0);
}

// ---------------- Pass 1: convert f32->bf16, permute feat rows into language
// buckets (row p = segbase[tok] + s*cnt[tok] + rank[b]); W converted linear. --
__global__ __launch_bounds__(256) void convert_permute_kernel(
    const float* __restrict__ feat,   // [S*B, F]
    const float* __restrict__ Wf,     // [L*E*F]
    const int*   __restrict__ toks,   // [B]
    unsigned short* __restrict__ Abf, // [S*B, F] permuted
    unsigned short* __restrict__ Wbf) // [L*E*F]
{
  __shared__ int stok[128];
  __shared__ int srank[128];
  __shared__ int scnt[8];
  __shared__ int sbase[8];            // in rows (512 * cumulative count)

  const int tid = threadIdx.x;
  if (tid < 128) stok[tid] = toks[tid];
  __syncthreads();
  if (tid < 128) {
    int myt = stok[tid], r = 0;
    for (int j = 0; j < 128; ++j) r += (j < tid) && (stok[j] == myt);
    srank[tid] = r;
  }
  if (tid < 8) {
    int c = 0;
    for (int j = 0; j < 128; ++j) c += (stok[j] == tid);
    scnt[tid] = c;
  }
  __syncthreads();
  if (tid < 8) {
    int b = 0;
    for (int j = 0; j < tid; ++j) b += scnt[j];
    sbase[tid] = b << 9;              // *512 rows
  }
  __syncthreads();

  const int FC = (SEQ * BATCH * FEAT) / 4;       // float4 chunks of feat
  const int TC = FC + (NLANG * EMBED * FEAT) / 4;
  for (int c = blockIdx.x * 256 + tid; c < TC; c += gridDim.x * 256) {
    if (c < FC) {
      float4 v = ((const float4*)feat)[c];
      const int r = c >> 8, q = c & 255;         // row, float4-within-row
      const int b = r & 127, s = r >> 7;
      const int tk = stok[b];
      const int p = sbase[tk] + s * scnt[tk] + srank[b];
      uint2 o; o.x = pk2(v.x, v.y); o.y = pk2(v.z, v.w);
      *(uint2*)(Abf + ((size_t)p << 10) + (q << 2)) = o;
    } else {
      const int c2 = c - FC;
      float4 v = ((const float4*)Wf)[c2];
      uint2 o; o.x = pk2(v.x, v.y); o.y = pk2(v.z, v.w);
      *(uint2*)(Wbf + ((size_t)c2 << 2)) = o;
    }
  }
}

// ---------------- Pass 2: m97-structure grouped GEMM, bf16 inputs. ----------
// 128x128 tile, BK=64, 4 waves (2x2), wave = 64x64 via 4x4 mfma_f32_16x16x32.
// Linear LDS [128][64], global_load_lds width=16, 2 barriers per K-step.
__global__ __launch_bounds__(256, 3) void grouped_gemm_bf16(
    const unsigned short* __restrict__ Abf,  // [S*B, F] bucket-permuted
    const unsigned short* __restrict__ Wbf,  // [L, E, F]
    const float* __restrict__ bias,          // [L, E]
    const int*   __restrict__ toks,          // [B]
    float*       __restrict__ out)           // [S*B, E] original order
{
  __shared__ unsigned short As[BM * BK];     // 16 KiB
  __shared__ unsigned short Bs[BN * BK];     // 16 KiB
  __shared__ int tokarr[128];
  __shared__ unsigned long long ballots[2][8];
  __shared__ int perm[128];
  __shared__ int rowsrc[128];

  const int tid  = threadIdx.x;
  const int lane = tid & 63;
  const int wv   = tid >> 6;
  const int wr   = wv >> 1;
  const int wc   = wv & 1;

  // XCD-aware mapping: 8 et-siblings of one mt adjacent within one XCD.
  const int bid = blockIdx.x;
  const int xcd = bid & 7;
  const int sq  = bid >> 3;
  const int et  = sq & 7;
  const int mt  = (sq >> 3) * 8 + xcd;
  const int m0  = mt * BM;
  const int e0  = et * BN;

  // ---- bucket setup (identical to verified R2 code) ----
  if (tid < 128) tokarr[tid] = toks[tid];
  __syncthreads();
  if (tid < 128) {
    int myt = tokarr[tid];
#pragma unroll
    for (int l = 0; l < 8; ++l) {
      unsigned long long bl = __ballot(myt == l);
      if (lane == 0) ballots[wv][l] = bl;
    }
  }
  __syncthreads();

  int lsel = 0, base = 0, csel = 1, boff_sel = 0;
  {
    int cum = 0, boff = 0;
#pragma unroll
    for (int l = 0; l < 8; ++l) {
      int c = __popcll(ballots[0][l]) + __popcll(ballots[1][l]);
      int seg = c << 9;
      bool in = (m0 >= cum) && (m0 < cum + seg);
      if (in) { lsel = l; base = cum; csel = c; boff_sel = boff; }
      cum += seg; boff += c;
    }
  }

  if (tid < 128) {
    int myt = tokarr[tid];
    unsigned long long ltm = (1ull << lane) - 1ull;
    int rank = (wv == 0) ? __popcll(ballots[0][myt] & ltm)
                         : __popcll(ballots[0][myt]) + __popcll(ballots[1][myt] & ltm);
    int boff2 = 0;
#pragma unroll
    for (int l = 0; l < 8; ++l) {
      int c = __popcll(ballots[0][l]) + __popcll(ballots[1][l]);
      boff2 += (l < myt) ? c : 0;
    }
    perm[boff2 + rank] = tid;
  }
  __syncthreads();
  if (tid < 128) {
    int local = m0 - base + tid;
    int s = local / csel;
    int j = local - s * csel;
    rowsrc[tid] = s * BATCH + perm[boff_sel + j];
  }
  // (rowsrc only read in epilogue; K-loop's first barrier orders it)

  // ---- staging addresses: per wave-instr i, 1 KiB = 8 rows x 128B.
  // LDS dest wave-uniform; lane l -> row +(l>>3), k-chunk (l&7)*8 elems. ----
  const unsigned short* aSrc[4];
  const unsigned short* bSrc[4];
  unsigned short* aDst[4];
  unsigned short* bDst[4];
#pragma unroll
  for (int i = 0; i < 4; ++i) {
    const int row = wv * 32 + i * 8 + (lane >> 3);
    const int k8  = (lane & 7) * 8;
    aSrc[i] = Abf + (size_t)(m0 + row) * FEAT + k8;
    bSrc[i] = Wbf + ((size_t)lsel * EMBED + e0 + row) * FEAT + k8;
    aDst[i] = &As[(wv * 32 + i * 8) * BK];
    bDst[i] = &Bs[(wv * 32 + i * 8) * BK];
  }

  f32x4 acc[4][4] = {};

  for (int k0 = 0; k0 < FEAT; k0 += BK) {
    __syncthreads();
#pragma unroll
    for (int i = 0; i < 4; ++i) {
      gld16(aSrc[i] + k0, aDst[i]);
      gld16(bSrc[i] + k0, bDst[i]);
    }
    __syncthreads();   // compiler drains vmcnt(0) before this barrier

#pragma unroll
    for (int kk = 0; kk < 2; ++kk) {
      const int ro = kk * 32 + (lane >> 4) * 8;   // ushort offset within row
      bf16x8 af[4], bfr[4];
#pragma unroll
      for (int mi = 0; mi < 4; ++mi)
        af[mi] = *(const bf16x8*)&As[(wr * 64 + mi * 16 + (lane & 15)) * BK + ro];
#pragma unroll
      for (int ni = 0; ni < 4; ++ni)
        bfr[ni] = *(const bf16x8*)&Bs[(wc * 64 + ni * 16 + (lane & 15)) * BK + ro];
#pragma unroll
      for (int mi = 0; mi < 4; ++mi)
#pragma unroll
        for (int ni = 0; ni < 4; ++ni)
          acc[mi][ni] = __builtin_amdgcn_mfma_f32_16x16x32_bf16(
              af[mi], bfr[ni], acc[mi][ni], 0, 0, 0);
    }
  }

  // ---- epilogue: col = lane&15 (-> e), row = (lane>>4)*4+j (-> m) ----
  const int col = lane & 15;
  const int r0  = (lane >> 4) * 4;
  float bvv[4];
#pragma unroll
  for (int ni = 0; ni < 4; ++ni)
    bvv[ni] = bias[lsel * EMBED + e0 + wc * 64 + ni * 16 + col];
#pragma unroll
  for (int mi = 0; mi < 4; ++mi) {
#pragma unroll
    for (int j = 0; j < 4; ++j) {
      const size_t ro2 = (size_t)rowsrc[wr * 64 + mi * 16 + r0 + j] * EMBED;
#pragma unroll
      for (int ni = 0; ni < 4; ++ni)
        out[ro2 + e0 + wc * 64 + ni * 16 + col] = acc[mi][ni][j] + bvv[ni];
    }
  }
}

// ---------------- Fallback (R2 fused kernel) if ws too small ----------------
__global__ __launch_bounds__(256, 2) void grouped_proj_fused(
    const float* __restrict__ feat, const float* __restrict__ Wt,
    const float* __restrict__ bias, const int* __restrict__ toks,
    float* __restrict__ out)
{
  __shared__ uint4 As[1024];
  __shared__ uint4 Bs[1024];
  __shared__ int tokarr[128];
  __shared__ unsigned long long ballots[2][8];
  __shared__ int perm[128];
  __shared__ int rowsrc[128];

  const int tid  = threadIdx.x;
  const int lane = tid & 63;
  const int wv   = tid >> 6;
  const int wr   = wv >> 1;
  const int wc   = wv & 1;
  const int bid = blockIdx.x;
  const int xcd = bid & 7;
  const int sq  = bid >> 3;
  const int et  = sq & 7;
  const int mt  = (sq >> 3) * 8 + xcd;
  const int m0  = mt * BM;
  const int e0  = et * BN;

  if (tid < 128) tokarr[tid] = toks[tid];
  __syncthreads();
  if (tid < 128) {
    int myt = tokarr[tid];
#pragma unroll
    for (int l = 0; l < 8; ++l) {
      unsigned long long bl = __ballot(myt == l);
      if (lane == 0) ballots[wv][l] = bl;
    }
  }
  __syncthreads();
  int lsel = 0, base = 0, csel = 1, boff_sel = 0;
  {
    int cum = 0, boff = 0;
#pragma unroll
    for (int l = 0; l < 8; ++l) {
      int c = __popcll(ballots[0][l]) + __popcll(ballots[1][l]);
      int seg = c << 9;
      bool in = (m0 >= cum) && (m0 < cum + seg);
      if (in) { lsel = l; base = cum; csel = c; boff_sel = boff; }
      cum += seg; boff += c;
    }
  }
  if (tid < 128) {
    int myt = tokarr[tid];
    unsigned long long ltm = (1ull << lane) - 1ull;
    int rank = (wv == 0) ? __popcll(ballots[0][myt] & ltm)
                         : __popcll(ballots[0][myt]) + __popcll(ballots[1][myt] & ltm);
    int boff2 = 0;
#pragma unroll
    for (int l = 0; l < 8; ++l) {
      int c = __popcll(ballots[0][l]) + __popcll(ballots[1][l]);
      boff2 += (l < myt) ? c : 0;
    }
    perm[boff2 + rank] = tid;
  }
  __syncthreads();
  if (tid < 128) {
    int local = m0 - base + tid;
    int s = local / csel;
    int j = local - s * csel;
    rowsrc[tid] = s * BATCH + perm[boff_sel + j];
  }
  __syncthreads();

  int slot_i[4];
  const float* aptr[4];
  const float* bptr[4];
#pragma unroll
  for (int it = 0; it < 4; ++it) {
    int c    = it * 256 + tid;
    int kg   = c & 7;
    int row  = c >> 3;
    int ksub = kg & 3;
    int kk   = kg >> 2;
    int frag = row >> 4;
    slot_i[it] = (kk * 8 + frag) * 64 + ((row & 15) ^ (ksub << 1) ^ kk) + ksub * 16;
    aptr[it] = feat + (size_t)rowsrc[row] * FEAT + kg * 8;
    bptr[it] = Wt + ((size_t)lsel * EMBED + e0 + row) * FEAT + kg * 8;
  }

  f32x4 acc[4][4] = {};
  for (int k0 = 0; k0 < FEAT; k0 += BK) {
    __syncthreads();
#pragma unroll
    for (int it = 0; it < 4; ++it) {
      float4 alo = *(const float4*)(aptr[it] + k0);
      float4 ahi = *(const float4*)(aptr[it] + k0 + 4);
      uint4 av;
      av.x = pk2(alo.x, alo.y); av.y = pk2(alo.z, alo.w);
      av.z = pk2(ahi.x, ahi.y); av.w = pk2(ahi.z, ahi.w);
      As[slot_i[it]] = av;
      float4 blo = *(const float4*)(bptr[it] + k0);
      float4 bhi = *(const float4*)(bptr[it] + k0 + 4);
      uint4 bv;
      bv.x = pk2(blo.x, blo.y); bv.y = pk2(blo.z, blo.w);
      bv.z = pk2(bhi.x, bhi.y); bv.w = pk2(bhi.z, bhi.w);
      Bs[slot_i[it]] = bv;
    }
    __syncthreads();
#pragma unroll
    for (int kk = 0; kk < 2; ++kk) {
      const int ksr = lane >> 4;
      const int sw  = ((lane & 15) ^ (ksr << 1) ^ kk) + ksr * 16;
      bf16x8 af[4], bfr[4];
#pragma unroll
      for (int mi = 0; mi < 4; ++mi)
        af[mi] = ((const bf16x8*)As)[(kk * 8 + wr * 4 + mi) * 64 + sw];
#pragma unroll
      for (int ni = 0; ni < 4; ++ni)
        bfr[ni] = ((const bf16x8*)Bs)[(kk * 8 + wc * 4 + ni) * 64 + sw];
#pragma unroll
      for (int mi = 0; mi < 4; ++mi)
#pragma unroll
        for (int ni = 0; ni < 4; ++ni)
          acc[mi][ni] = __builtin_amdgcn_mfma_f32_16x16x32_bf16(
              af[mi], bfr[ni], acc[mi][ni], 0, 0, 0);
    }
  }

  const int col = lane & 15;
  const int r0  = (lane >> 4) * 4;
  float bvv[4];
#pragma unroll
  for (int ni = 0; ni < 4; ++ni)
    bvv[ni] = bias[lsel * EMBED + e0 + wc * 64 + ni * 16 + col];
#pragma unroll
  for (int mi = 0; mi < 4; ++mi) {
#pragma unroll
    for (int j = 0; j < 4; ++j) {
      const size_t ro = (size_t)rowsrc[wr * 64 + mi * 16 + r0 + j] * EMBED;
#pragma unroll
      for (int ni = 0; ni < 4; ++ni)
        out[ro + e0 + wc * 64 + ni * 16 + col] = acc[mi][ni][j] + bvv[ni];
    }
  }
}

extern "C" void kernel_launch(void* const* d_in, const int* in_sizes, int n_in,
                              void* d_out, int out_size, void* d_ws, size_t ws_size,
                              hipStream_t stream) {
  const float* feat = (const float*)d_in[0];
  const float* W    = (const float*)d_in[1];
  const float* bias = (const float*)d_in[2];
  const int*   toks = (const int*)d_in[3];
  float* out = (float*)d_out;

  const size_t abf_bytes = (size_t)SEQ * BATCH * FEAT * 2;        // 128 MiB
  const size_t wbf_bytes = (size_t)NLANG * EMBED * FEAT * 2;      // 16 MiB

  if (ws_size >= abf_bytes + wbf_bytes) {
    unsigned short* Abf = (unsigned short*)d_ws;
    unsigned short* Wbf = (unsigned short*)((char*)d_ws + abf_bytes);
    convert_permute_kernel<<<3072, 256, 0, stream>>>(feat, W, toks, Abf, Wbf);
    grouped_gemm_bf16<<<(SEQ * BATCH / BM) * (EMBED / BN), 256, 0, stream>>>(
        Abf, Wbf, bias, toks, out);
  } else {
    grouped_proj_fused<<<(SEQ * BATCH / BM) * (EMBED / BN), 256, 0, stream>>>(
        feat, W, bias, toks, out);
  }
}

// Round 4
// 261.934 us; speedup vs baseline: 3.1010x; 1.1750x over previous
//
#include <hip/hip_runtime.h>
#include <hip/hip_bf16.h>

#define SEQ   512
#define BATCH 128
#define FEAT  1024
#define EMBED 1024
#define NLANG 8

typedef __attribute__((ext_vector_type(8))) short bf16x8;
typedef __attribute__((ext_vector_type(4))) float f32x4;
typedef unsigned short ushort_t;

__device__ __forceinline__ unsigned pk2(float a, float b) {
  float2 f; f.x = a; f.y = b;
  __hip_bfloat162 h = __float22bfloat162_rn(f);   // v_cvt_pk_bf16_f32
  union { __hip_bfloat162 h2; unsigned u; } cv;
  cv.h2 = h;
  return cv.u;
}

__device__ __forceinline__ void gld16(const void* g, void* l) {
  __builtin_amdgcn_global_load_lds(
      (const __attribute__((address_space(1))) void*)g,
      (__attribute__((address_space(3))) void*)l, 16, 0, 0);
}

// ---------------- Pass 1: f32->bf16 convert; feat rows permuted into language
// buckets (row p = segbase[tok] + s*cnt[tok] + rank[b]); W converted linear. --
__global__ __launch_bounds__(256) void convert_permute_kernel(
    const float* __restrict__ feat,   // [S*B, F]
    const float* __restrict__ Wf,     // [L*E*F]
    const int*   __restrict__ toks,   // [B]
    ushort_t* __restrict__ Abf,       // [S*B, F] permuted
    ushort_t* __restrict__ Wbf)       // [L*E*F]
{
  __shared__ int stok[128];
  __shared__ int srank[128];
  __shared__ int scnt[8];
  __shared__ int sbase[8];

  const int tid = threadIdx.x;
  if (tid < 128) stok[tid] = toks[tid];
  __syncthreads();
  if (tid < 128) {
    int myt = stok[tid], r = 0;
    for (int j = 0; j < 128; ++j) r += (j < tid) && (stok[j] == myt);
    srank[tid] = r;
  }
  if (tid < 8) {
    int c = 0;
    for (int j = 0; j < 128; ++j) c += (stok[j] == tid);
    scnt[tid] = c;
  }
  __syncthreads();
  if (tid < 8) {
    int b = 0;
    for (int j = 0; j < tid; ++j) b += scnt[j];
    sbase[tid] = b << 9;
  }
  __syncthreads();

  const int FC = (SEQ * BATCH * FEAT) / 4;
  const int TC = FC + (NLANG * EMBED * FEAT) / 4;
  for (int c = blockIdx.x * 256 + tid; c < TC; c += gridDim.x * 256) {
    if (c < FC) {
      float4 v = ((const float4*)feat)[c];
      const int r = c >> 8, q = c & 255;
      const int b = r & 127, s = r >> 7;
      const int tk = stok[b];
      const int p = sbase[tk] + s * scnt[tk] + srank[b];
      uint2 o; o.x = pk2(v.x, v.y); o.y = pk2(v.z, v.w);
      *(uint2*)(Abf + ((size_t)p << 10) + (q << 2)) = o;
    } else {
      const int c2 = c - FC;
      float4 v = ((const float4*)Wf)[c2];
      uint2 o; o.x = pk2(v.x, v.y); o.y = pk2(v.z, v.w);
      *(uint2*)(Wbf + ((size_t)c2 << 2)) = o;
    }
  }
}

// ---------------- Pass 2: pipelined 256x256 grouped GEMM, BK=32, 4-buffer
// LDS ring, counted vmcnt(8), raw barriers, XOR bank swizzle, setprio. ------
// 512 threads = 8 waves (2M x 4N); per-wave 128x64 out via acc[8][4] of
// mfma_f32_16x16x32_bf16. LDS dynamic 128 KiB: A bufs [0,64K), B [64K,128K).
__global__ __launch_bounds__(512, 2) void grouped_gemm_pipe(
    const ushort_t* __restrict__ Abf,  // [S*B, F] bucket-permuted bf16
    const ushort_t* __restrict__ Wbf,  // [L, E, F] bf16
    const float* __restrict__ bias,    // [L, E]
    const int*   __restrict__ toks,    // [B]
    float*       __restrict__ out)     // [S*B, E] original order
{
  extern __shared__ ushort_t lds[];          // 65536 ushort = 128 KiB
  __shared__ int tokarr[128];
  __shared__ unsigned long long ballots[2][8];
  __shared__ int perm[128];
  __shared__ int rowsrc[256];

  const int tid = threadIdx.x;
  const int l   = tid & 63;
  const int w   = tid >> 6;
  const int wr  = w >> 2;                    // 0..1 (M half)
  const int wc  = w & 3;                     // 0..3 (N quarter)

  // XCD-chunked bijective swizzle: XCD x owns mt in [x*32, x*32+32); the 4
  // et-siblings of an mt dispatch within 32 consecutive bids on one XCD.
  const int bid = blockIdx.x;
  const int L   = (bid & 7) * 128 + (bid >> 3);
  const int et  = L & 3;
  const int mt  = (L >> 7) * 32 + ((L >> 2) & 31);
  const int m0  = mt * 256;
  const int e0  = et * 256;

  // ---- bucket setup (ballot histogram + rank; only waves 0,1 vote) ----
  if (tid < 128) tokarr[tid] = toks[tid];
  __syncthreads();
  if (tid < 128) {
    int myt = tokarr[tid];
#pragma unroll
    for (int lg = 0; lg < 8; ++lg) {
      unsigned long long bl = __ballot(myt == lg);
      if (l == 0) ballots[w][lg] = bl;
    }
  }
  __syncthreads();

  int lsel = 0, base = 0, csel = 1, boff_sel = 0;
  {
    int cum = 0, boff = 0;
#pragma unroll
    for (int lg = 0; lg < 8; ++lg) {
      int c = __popcll(ballots[0][lg]) + __popcll(ballots[1][lg]);
      int seg = c << 9;
      bool in = (m0 >= cum) && (m0 < cum + seg);
      if (in) { lsel = lg; base = cum; csel = c; boff_sel = boff; }
      cum += seg; boff += c;
    }
  }

  if (tid < 128) {
    int myt = tokarr[tid];
    unsigned long long ltm = (1ull << l) - 1ull;
    int rank = (w == 0) ? __popcll(ballots[0][myt] & ltm)
                        : __popcll(ballots[0][myt]) + __popcll(ballots[1][myt] & ltm);
    int boff2 = 0;
#pragma unroll
    for (int lg = 0; lg < 8; ++lg) {
      int c = __popcll(ballots[0][lg]) + __popcll(ballots[1][lg]);
      boff2 += (lg < myt) ? c : 0;
    }
    perm[boff2 + rank] = tid;
  }
  __syncthreads();
  if (tid < 256) {
    int local = m0 - base + tid;
    int s = local / csel;
    int j = local - s * csel;
    rowsrc[tid] = s * BATCH + perm[boff_sel + j];
  }
  __syncthreads();

  // ---- staging: K-tile = 256 rows x 32 k x bf16 = 16 KiB = 1024 chunks of
  // 16B. chunk c = row*4 + cc. Thread handles chunks c0=w*128+l, c1=c0+64.
  // Source k-chunk = cc ^ ((row>>1)&3)  (inverse swizzle; involution), so the
  // LINEAR LDS chunk (row,cc) holds global k-chunk cc^s -> swizzled reads are
  // 8-lanes-per-bank-quad (conflict-free). s(row)==s(row+16): one addr pair. -
  const int ca   = w * 128 + l;
  const int rwA  = ca >> 2;                   // row for i=0 (i=1 -> +16)
  const int ccA  = ca & 3;
  const int sA   = (rwA >> 1) & 3;
  const ushort_t* aS0 = Abf + (size_t)(m0 + rwA) * FEAT + ((ccA ^ sA) * 8);
  const ushort_t* aS1 = aS0 + (size_t)16 * FEAT;
  const ushort_t* bS0 = Wbf + ((size_t)lsel * EMBED + e0 + rwA) * FEAT + ((ccA ^ sA) * 8);
  const ushort_t* bS1 = bS0 + (size_t)16 * FEAT;
  const int dOff0 = (w * 128) * 8;            // ushort units within a buf
  const int dOff1 = (w * 128 + 64) * 8;

  // ---- read offsets (ushort units, within a buf): row*32 + (kc^s(row))*8 ----
  const int kc  = l >> 4;
  const int rA  = wr * 128 + (l & 15);
  const int aRd = rA * 32 + ((kc ^ ((rA >> 1) & 3)) * 8);
  const int rB  = wc * 64 + (l & 15);
  const int bRd = rB * 32 + ((kc ^ ((rB >> 1) & 3)) * 8);

  f32x4 acc[8][4] = {};

#define STAGE(kt, buf)                                                     \
  do {                                                                     \
    const int _o = (kt) * 32;                                              \
    gld16(aS0 + _o, lds + (buf) * 8192 + dOff0);                           \
    gld16(aS1 + _o, lds + (buf) * 8192 + dOff1);                           \
    gld16(bS0 + _o, lds + 32768 + (buf) * 8192 + dOff0);                   \
    gld16(bS1 + _o, lds + 32768 + (buf) * 8192 + dOff1);                   \
  } while (0)

  // prologue: stage K-tiles 0,1,2 -> bufs 0,1,2; wait so tile 0 resident.
  STAGE(0, 0);
  STAGE(1, 1);
  STAGE(2, 2);
  asm volatile("s_waitcnt vmcnt(8)" ::: "memory");
  __builtin_amdgcn_s_barrier();
  __builtin_amdgcn_sched_barrier(0);

  const int NT = FEAT / 32;                   // 32 K-tiles
  for (int t = 0; t < NT; ++t) {
    const ushort_t* Ab = lds + (t & 3) * 8192;
    const ushort_t* Bb = lds + 32768 + (t & 3) * 8192;
    if (t < NT - 3) STAGE(t + 3, (t + 3) & 3);

    bf16x8 af[8], bfq[4];
#pragma unroll
    for (int mf = 0; mf < 8; ++mf)
      af[mf] = *(const bf16x8*)(Ab + aRd + mf * 512);
#pragma unroll
    for (int nf = 0; nf < 4; ++nf)
      bfq[nf] = *(const bf16x8*)(Bb + bRd + nf * 512);

    __builtin_amdgcn_s_setprio(1);
#pragma unroll
    for (int mf = 0; mf < 8; ++mf)
#pragma unroll
      for (int nf = 0; nf < 4; ++nf)
        acc[mf][nf] = __builtin_amdgcn_mfma_f32_16x16x32_bf16(
            af[mf], bfq[nf], acc[mf][nf], 0, 0, 0);
    __builtin_amdgcn_s_setprio(0);

    // counted waits: never 0 in steady state (3 K-tiles in flight).
    if (t < NT - 3)       asm volatile("s_waitcnt vmcnt(8)" ::: "memory");
    else if (t == NT - 3) asm volatile("s_waitcnt vmcnt(4)" ::: "memory");
    else if (t == NT - 2) asm volatile("s_waitcnt vmcnt(0)" ::: "memory");
    if (t < NT - 1) {
      __builtin_amdgcn_s_barrier();
      __builtin_amdgcn_sched_barrier(0);
    }
  }
#undef STAGE

  // ---- epilogue: C/D col = lane&15 (-> e), row = (lane>>4)*4+j (-> m) ----
  const int col = l & 15;
  const int r4  = (l >> 4) * 4;
  float bvv[4];
#pragma unroll
  for (int nf = 0; nf < 4; ++nf)
    bvv[nf] = bias[lsel * EMBED + e0 + wc * 64 + nf * 16 + col];
#pragma unroll
  for (int mf = 0; mf < 8; ++mf) {
#pragma unroll
    for (int j = 0; j < 4; ++j) {
      const size_t ro = (size_t)rowsrc[wr * 128 + mf * 16 + r4 + j] * EMBED;
#pragma unroll
      for (int nf = 0; nf < 4; ++nf)
        out[ro + e0 + wc * 64 + nf * 16 + col] = acc[mf][nf][j] + bvv[nf];
    }
  }
}

// ---------------- Fallback (R2 fused kernel) if ws too small ----------------
__global__ __launch_bounds__(256, 2) void grouped_proj_fused(
    const float* __restrict__ feat, const float* __restrict__ Wt,
    const float* __restrict__ bias, const int* __restrict__ toks,
    float* __restrict__ out)
{
  __shared__ uint4 As[1024];
  __shared__ uint4 Bs[1024];
  __shared__ int tokarr[128];
  __shared__ unsigned long long ballots[2][8];
  __shared__ int perm[128];
  __shared__ int rowsrc[128];

  const int tid  = threadIdx.x;
  const int lane = tid & 63;
  const int wv   = tid >> 6;
  const int wr   = wv >> 1;
  const int wc   = wv & 1;
  const int bid = blockIdx.x;
  const int xcd = bid & 7;
  const int sq  = bid >> 3;
  const int et  = sq & 7;
  const int mt  = (sq >> 3) * 8 + xcd;
  const int m0  = mt * 128;
  const int e0  = et * 128;

  if (tid < 128) tokarr[tid] = toks[tid];
  __syncthreads();
  if (tid < 128) {
    int myt = tokarr[tid];
#pragma unroll
    for (int lg = 0; lg < 8; ++lg) {
      unsigned long long bl = __ballot(myt == lg);
      if (lane == 0) ballots[wv][lg] = bl;
    }
  }
  __syncthreads();
  int lsel = 0, base = 0, csel = 1, boff_sel = 0;
  {
    int cum = 0, boff = 0;
#pragma unroll
    for (int lg = 0; lg < 8; ++lg) {
      int c = __popcll(ballots[0][lg]) + __popcll(ballots[1][lg]);
      int seg = c << 9;
      bool in = (m0 >= cum) && (m0 < cum + seg);
      if (in) { lsel = lg; base = cum; csel = c; boff_sel = boff; }
      cum += seg; boff += c;
    }
  }
  if (tid < 128) {
    int myt = tokarr[tid];
    unsigned long long ltm = (1ull << lane) - 1ull;
    int rank = (wv == 0) ? __popcll(ballots[0][myt] & ltm)
                         : __popcll(ballots[0][myt]) + __popcll(ballots[1][myt] & ltm);
    int boff2 = 0;
#pragma unroll
    for (int lg = 0; lg < 8; ++lg) {
      int c = __popcll(ballots[0][lg]) + __popcll(ballots[1][lg]);
      boff2 += (lg < myt) ? c : 0;
    }
    perm[boff2 + rank] = tid;
  }
  __syncthreads();
  if (tid < 128) {
    int local = m0 - base + tid;
    int s = local / csel;
    int j = local - s * csel;
    rowsrc[tid] = s * BATCH + perm[boff_sel + j];
  }
  __syncthreads();

  int slot_i[4];
  const float* aptr[4];
  const float* bptr[4];
#pragma unroll
  for (int it = 0; it < 4; ++it) {
    int c    = it * 256 + tid;
    int kg   = c & 7;
    int row  = c >> 3;
    int ksub = kg & 3;
    int kk   = kg >> 2;
    int frag = row >> 4;
    slot_i[it] = (kk * 8 + frag) * 64 + ((row & 15) ^ (ksub << 1) ^ kk) + ksub * 16;
    aptr[it] = feat + (size_t)rowsrc[row] * FEAT + kg * 8;
    bptr[it] = Wt + ((size_t)lsel * EMBED + e0 + row) * FEAT + kg * 8;
  }

  f32x4 acc[4][4] = {};
  for (int k0 = 0; k0 < FEAT; k0 += 64) {
    __syncthreads();
#pragma unroll
    for (int it = 0; it < 4; ++it) {
      float4 alo = *(const float4*)(aptr[it] + k0);
      float4 ahi = *(const float4*)(aptr[it] + k0 + 4);
      uint4 av;
      av.x = pk2(alo.x, alo.y); av.y = pk2(alo.z, alo.w);
      av.z = pk2(ahi.x, ahi.y); av.w = pk2(ahi.z, ahi.w);
      As[slot_i[it]] = av;
      float4 blo = *(const float4*)(bptr[it] + k0);
      float4 bhi = *(const float4*)(bptr[it] + k0 + 4);
      uint4 bv;
      bv.x = pk2(blo.x, blo.y); bv.y = pk2(blo.z, blo.w);
      bv.z = pk2(bhi.x, bhi.y); bv.w = pk2(bhi.z, bhi.w);
      Bs[slot_i[it]] = bv;
    }
    __syncthreads();
#pragma unroll
    for (int kk = 0; kk < 2; ++kk) {
      const int ksr = lane >> 4;
      const int sw  = ((lane & 15) ^ (ksr << 1) ^ kk) + ksr * 16;
      bf16x8 af[4], bfr[4];
#pragma unroll
      for (int mi = 0; mi < 4; ++mi)
        af[mi] = ((const bf16x8*)As)[(kk * 8 + wr * 4 + mi) * 64 + sw];
#pragma unroll
      for (int ni = 0; ni < 4; ++ni)
        bfr[ni] = ((const bf16x8*)Bs)[(kk * 8 + wc * 4 + ni) * 64 + sw];
#pragma unroll
      for (int mi = 0; mi < 4; ++mi)
#pragma unroll
        for (int ni = 0; ni < 4; ++ni)
          acc[mi][ni] = __builtin_amdgcn_mfma_f32_16x16x32_bf16(
              af[mi], bfr[ni], acc[mi][ni], 0, 0, 0);
    }
  }

  const int col = lane & 15;
  const int r0  = (lane >> 4) * 4;
  float bvv[4];
#pragma unroll
  for (int ni = 0; ni < 4; ++ni)
    bvv[ni] = bias[lsel * EMBED + e0 + wc * 64 + ni * 16 + col];
#pragma unroll
  for (int mi = 0; mi < 4; ++mi) {
#pragma unroll
    for (int j = 0; j < 4; ++j) {
      const size_t ro = (size_t)rowsrc[wr * 64 + mi * 16 + r0 + j] * EMBED;
#pragma unroll
      for (int ni = 0; ni < 4; ++ni)
        out[ro + e0 + wc * 64 + ni * 16 + col] = acc[mi][ni][j] + bvv[ni];
    }
  }
}

extern "C" void kernel_launch(void* const* d_in, const int* in_sizes, int n_in,
                              void* d_out, int out_size, void* d_ws, size_t ws_size,
                              hipStream_t stream) {
  const float* feat = (const float*)d_in[0];
  const float* W    = (const float*)d_in[1];
  const float* bias = (const float*)d_in[2];
  const int*   toks = (const int*)d_in[3];
  float* out = (float*)d_out;

  const size_t abf_bytes = (size_t)SEQ * BATCH * FEAT * 2;        // 128 MiB
  const size_t wbf_bytes = (size_t)NLANG * EMBED * FEAT * 2;      // 16 MiB

  if (ws_size >= abf_bytes + wbf_bytes) {
    ushort_t* Abf = (ushort_t*)d_ws;
    ushort_t* Wbf = (ushort_t*)((char*)d_ws + abf_bytes);
    convert_permute_kernel<<<3072, 256, 0, stream>>>(feat, W, toks, Abf, Wbf);
    (void)hipFuncSetAttribute((const void*)grouped_gemm_pipe,
                              hipFuncAttributeMaxDynamicSharedMemorySize, 131072);
    const int nblk = (SEQ * BATCH / 256) * (EMBED / 256);         // 1024
    grouped_gemm_pipe<<<nblk, 512, 131072, stream>>>(Abf, Wbf, bias, toks, out);
  } else {
    grouped_proj_fused<<<(SEQ * BATCH / 128) * (EMBED / 128), 256, 0, stream>>>(
        feat, W, bias, toks, out);
  }
}

// Round 5
// 260.736 us; speedup vs baseline: 3.1153x; 1.0046x over previous
//
#include <hip/hip_runtime.h>
#include <hip/hip_bf16.h>

#define SEQ   512
#define BATCH 128
#define FEAT  1024
#define EMBED 1024
#define NLANG 8

typedef __attribute__((ext_vector_type(8))) short bf16x8;
typedef __attribute__((ext_vector_type(4))) float f32x4;
typedef unsigned short ushort_t;

__device__ __forceinline__ unsigned pk2(float a, float b) {
  float2 f; f.x = a; f.y = b;
  __hip_bfloat162 h = __float22bfloat162_rn(f);   // v_cvt_pk_bf16_f32
  union { __hip_bfloat162 h2; unsigned u; } cv;
  cv.h2 = h;
  return cv.u;
}

__device__ __forceinline__ void gld16(const void* g, void* l) {
  __builtin_amdgcn_global_load_lds(
      (const __attribute__((address_space(1))) void*)g,
      (__attribute__((address_space(3))) void*)l, 16, 0, 0);
}

// ---------------- Pass 1: f32->bf16 convert; feat rows permuted into language
// buckets (row p = segbase[tok] + s*cnt[tok] + rank[b]); W converted linear. --
__global__ __launch_bounds__(256) void convert_permute_kernel(
    const float* __restrict__ feat,   // [S*B, F]
    const float* __restrict__ Wf,     // [L*E*F]
    const int*   __restrict__ toks,   // [B]
    ushort_t* __restrict__ Abf,       // [S*B, F] permuted
    ushort_t* __restrict__ Wbf)       // [L*E*F]
{
  __shared__ int stok[128];
  __shared__ int srank[128];
  __shared__ int scnt[8];
  __shared__ int sbase[8];

  const int tid = threadIdx.x;
  if (tid < 128) stok[tid] = toks[tid];
  __syncthreads();
  if (tid < 128) {
    int myt = stok[tid], r = 0;
    for (int j = 0; j < 128; ++j) r += (j < tid) && (stok[j] == myt);
    srank[tid] = r;
  }
  if (tid < 8) {
    int c = 0;
    for (int j = 0; j < 128; ++j) c += (stok[j] == tid);
    scnt[tid] = c;
  }
  __syncthreads();
  if (tid < 8) {
    int b = 0;
    for (int j = 0; j < tid; ++j) b += scnt[j];
    sbase[tid] = b << 9;
  }
  __syncthreads();

  const int FC = (SEQ * BATCH * FEAT) / 4;
  const int TC = FC + (NLANG * EMBED * FEAT) / 4;
  for (int c = blockIdx.x * 256 + tid; c < TC; c += gridDim.x * 256) {
    if (c < FC) {
      float4 v = ((const float4*)feat)[c];
      const int r = c >> 8, q = c & 255;
      const int b = r & 127, s = r >> 7;
      const int tk = stok[b];
      const int p = sbase[tk] + s * scnt[tk] + srank[b];
      uint2 o; o.x = pk2(v.x, v.y); o.y = pk2(v.z, v.w);
      *(uint2*)(Abf + ((size_t)p << 10) + (q << 2)) = o;
    } else {
      const int c2 = c - FC;
      float4 v = ((const float4*)Wf)[c2];
      uint2 o; o.x = pk2(v.x, v.y); o.y = pk2(v.z, v.w);
      *(uint2*)(Wbf + ((size_t)c2 << 2)) = o;
    }
  }
}

// ---------------- Pass 2: phase-split pipelined 256x256 grouped GEMM --------
// BK=32 granules, ring of 4 LDS bufs, counted vmcnt(8), 2 phases of 16 MFMA
// per granule (T3), setprio (T5), XOR bank swizzle (T2-equivalent, verified
// conflict-free in R4). 512 threads = 8 waves (2M x 4N); wave = 128x64 out.
__global__ __launch_bounds__(512, 2) void grouped_gemm_8ph(
    const ushort_t* __restrict__ Abf,  // [S*B, F] bucket-permuted bf16
    const ushort_t* __restrict__ Wbf,  // [L, E, F] bf16
    const float* __restrict__ bias,    // [L, E]
    const int*   __restrict__ toks,    // [B]
    float*       __restrict__ out)     // [S*B, E] original order
{
  extern __shared__ ushort_t lds[];          // 128 KiB dynamic
  __shared__ int tokarr[128];
  __shared__ unsigned long long ballots[2][8];
  __shared__ int perm[128];
  __shared__ int rowsrc[256];

  const int tid = threadIdx.x;
  const int l   = tid & 63;
  const int w   = tid >> 6;
  const int wr  = w >> 2;                    // 0..1 (M half)
  const int wc  = w & 3;                     // 0..3 (N quarter)

  // XCD-chunked bijective swizzle (1024 blocks = 8 XCDs x 128).
  const int bid = blockIdx.x;
  const int L   = (bid & 7) * 128 + (bid >> 3);
  const int et  = L & 3;
  const int mt  = (L >> 7) * 32 + ((L >> 2) & 31);
  const int m0  = mt * 256;
  const int e0  = et * 256;

  // ---- bucket setup (ballot histogram + rank; waves 0,1 vote) ----
  if (tid < 128) tokarr[tid] = toks[tid];
  __syncthreads();
  if (tid < 128) {
    int myt = tokarr[tid];
#pragma unroll
    for (int lg = 0; lg < 8; ++lg) {
      unsigned long long bl = __ballot(myt == lg);
      if (l == 0) ballots[w][lg] = bl;
    }
  }
  __syncthreads();

  int lsel = 0, base = 0, csel = 1, boff_sel = 0;
  {
    int cum = 0, boff = 0;
#pragma unroll
    for (int lg = 0; lg < 8; ++lg) {
      int c = __popcll(ballots[0][lg]) + __popcll(ballots[1][lg]);
      int seg = c << 9;
      bool in = (m0 >= cum) && (m0 < cum + seg);
      if (in) { lsel = lg; base = cum; csel = c; boff_sel = boff; }
      cum += seg; boff += c;
    }
  }

  if (tid < 128) {
    int myt = tokarr[tid];
    unsigned long long ltm = (1ull << l) - 1ull;
    int rank = (w == 0) ? __popcll(ballots[0][myt] & ltm)
                        : __popcll(ballots[0][myt]) + __popcll(ballots[1][myt] & ltm);
    int boff2 = 0;
#pragma unroll
    for (int lg = 0; lg < 8; ++lg) {
      int c = __popcll(ballots[0][lg]) + __popcll(ballots[1][lg]);
      boff2 += (lg < myt) ? c : 0;
    }
    perm[boff2 + rank] = tid;
  }
  __syncthreads();
  if (tid < 256) {
    int local = m0 - base + tid;
    int s = local / csel;
    int j = local - s * csel;
    rowsrc[tid] = s * BATCH + perm[boff_sel + j];
  }
  __syncthreads();

  // ---- staging (identical addressing to R4, verified conflict-free):
  // granule = 256 rows x 32 k = 16 KiB = 1024 chunks of 16B; chunk c=row*4+cc;
  // thread handles chunks c0=w*128+l, c1=c0+64 (rows rwA, rwA+16).
  // Source k-chunk = cc ^ ((row>>1)&3); swizzled ds_read matches. ----
  const int ca   = w * 128 + l;
  const int rwA  = ca >> 2;
  const int ccA  = ca & 3;
  const int sA   = (rwA >> 1) & 3;
  const ushort_t* aS0 = Abf + (size_t)(m0 + rwA) * FEAT + ((ccA ^ sA) * 8);
  const ushort_t* aS1 = aS0 + (size_t)16 * FEAT;
  const ushort_t* bS0 = Wbf + ((size_t)lsel * EMBED + e0 + rwA) * FEAT + ((ccA ^ sA) * 8);
  const ushort_t* bS1 = bS0 + (size_t)16 * FEAT;
  const int dOff0 = (w * 128) * 8;            // ushort units within a buf
  const int dOff1 = (w * 128 + 64) * 8;

  // ---- fragment read offsets (ushort units within a buf) ----
  const int kc  = l >> 4;
  const int rA  = wr * 128 + (l & 15);
  const int aRd = rA * 32 + ((kc ^ ((rA >> 1) & 3)) * 8);
  const int rB  = wc * 64 + (l & 15);
  const int bRd = rB * 32 + ((kc ^ ((rB >> 1) & 3)) * 8);

  f32x4 acc[8][4] = {};
  bf16x8 af0[4], af1[4], bfq[4];

#define STAGE_A(kt, buf)                                                   \
  do { const int _o = (kt) * 32;                                           \
    gld16(aS0 + _o, lds + (buf) * 8192 + dOff0);                           \
    gld16(aS1 + _o, lds + (buf) * 8192 + dOff1); } while (0)
#define STAGE_B(kt, buf)                                                   \
  do { const int _o = (kt) * 32;                                           \
    gld16(bS0 + _o, lds + 32768 + (buf) * 8192 + dOff0);                   \
    gld16(bS1 + _o, lds + 32768 + (buf) * 8192 + dOff1); } while (0)

// Phase 0 of granule g: read A m-half0 + all B, stage A of g+3, MFMA acc[0-3].
#define PH0(g, DOSTAGE)                                                    \
  do {                                                                     \
    const ushort_t* Ab_ = lds + ((g) & 3) * 8192;                          \
    const ushort_t* Bb_ = lds + 32768 + ((g) & 3) * 8192;                  \
    _Pragma("unroll") for (int mf = 0; mf < 4; ++mf)                       \
        af0[mf] = *(const bf16x8*)(Ab_ + aRd + mf * 512);                  \
    _Pragma("unroll") for (int nf = 0; nf < 4; ++nf)                       \
        bfq[nf] = *(const bf16x8*)(Bb_ + bRd + nf * 512);                  \
    if (DOSTAGE) { STAGE_A((g) + 3, ((g) + 3) & 3); }                      \
    __builtin_amdgcn_sched_barrier(0);                                     \
    __builtin_amdgcn_s_barrier();                                          \
    asm volatile("s_waitcnt lgkmcnt(0)" ::: "memory");                     \
    __builtin_amdgcn_sched_barrier(0);                                     \
    __builtin_amdgcn_s_setprio(1);                                         \
    _Pragma("unroll") for (int mf = 0; mf < 4; ++mf)                       \
        _Pragma("unroll") for (int nf = 0; nf < 4; ++nf)                   \
            acc[mf][nf] = __builtin_amdgcn_mfma_f32_16x16x32_bf16(         \
                af0[mf], bfq[nf], acc[mf][nf], 0, 0, 0);                   \
    __builtin_amdgcn_s_setprio(0);                                         \
    __builtin_amdgcn_s_barrier();                                          \
  } while (0)

// Phase 1 of granule g: read A m-half1, stage B of g+3, MFMA acc[4-7],
// counted vmcnt before closing barrier (WAIT literal).
#define PH1(g, DOSTAGE, WAIT)                                              \
  do {                                                                     \
    const ushort_t* Ab_ = lds + ((g) & 3) * 8192;                          \
    _Pragma("unroll") for (int mf = 0; mf < 4; ++mf)                       \
        af1[mf] = *(const bf16x8*)(Ab_ + aRd + (mf + 4) * 512);            \
    if (DOSTAGE) { STAGE_B((g) + 3, ((g) + 3) & 3); }                      \
    __builtin_amdgcn_sched_barrier(0);                                     \
    __builtin_amdgcn_s_barrier();                                          \
    asm volatile("s_waitcnt lgkmcnt(0)" ::: "memory");                     \
    __builtin_amdgcn_sched_barrier(0);                                     \
    __builtin_amdgcn_s_setprio(1);                                         \
    _Pragma("unroll") for (int mf = 0; mf < 4; ++mf)                       \
        _Pragma("unroll") for (int nf = 0; nf < 4; ++nf)                   \
            acc[mf + 4][nf] = __builtin_amdgcn_mfma_f32_16x16x32_bf16(     \
                af1[mf], bfq[nf], acc[mf + 4][nf], 0, 0, 0);               \
    __builtin_amdgcn_s_setprio(0);                                         \
    asm volatile(WAIT ::: "memory");                                       \
    __builtin_amdgcn_s_barrier();                                          \
  } while (0)

  // prologue: stage granules 0,1,2 (12 loads); granule 0 resident after
  // vmcnt(8) (in-order retire leaves granules 1,2 outstanding).
  STAGE_A(0, 0); STAGE_B(0, 0);
  STAGE_A(1, 1); STAGE_B(1, 1);
  STAGE_A(2, 2); STAGE_B(2, 2);
  asm volatile("s_waitcnt vmcnt(8)" ::: "memory");
  __builtin_amdgcn_s_barrier();
  __builtin_amdgcn_sched_barrier(0);

  // steady state: granule g reads buf g&3, stages granule g+3 (buf (g+3)&3,
  // disjoint from bufs g&3,(g+1)&3 in active use). vmcnt(8) at ph1-end
  // retires granule g+1's 4 loads (8 newer remain: iters g-1,g stagings).
  for (int g = 0; g < 29; ++g) {
    PH0(g, true);
    PH1(g, true, "s_waitcnt vmcnt(8)");
  }
  // tail: no staging; wait counts shrink 4 -> 0.
  PH0(29, false); PH1(29, false, "s_waitcnt vmcnt(4)");
  PH0(30, false); PH1(30, false, "s_waitcnt vmcnt(0)");
  PH0(31, false); PH1(31, false, "s_nop 0");

#undef PH0
#undef PH1
#undef STAGE_A
#undef STAGE_B

  // ---- epilogue: C/D col = lane&15 (-> e), row = (lane>>4)*4+j (-> m) ----
  const int col = l & 15;
  const int r4  = (l >> 4) * 4;
  float bvv[4];
#pragma unroll
  for (int nf = 0; nf < 4; ++nf)
    bvv[nf] = bias[lsel * EMBED + e0 + wc * 64 + nf * 16 + col];
#pragma unroll
  for (int mf = 0; mf < 8; ++mf) {
#pragma unroll
    for (int j = 0; j < 4; ++j) {
      const size_t ro = (size_t)rowsrc[wr * 128 + mf * 16 + r4 + j] * EMBED;
#pragma unroll
      for (int nf = 0; nf < 4; ++nf)
        out[ro + e0 + wc * 64 + nf * 16 + col] = acc[mf][nf][j] + bvv[nf];
    }
  }
}

// ---------------- Fallback (R2 fused kernel) if ws too small ----------------
__global__ __launch_bounds__(256, 2) void grouped_proj_fused(
    const float* __restrict__ feat, const float* __restrict__ Wt,
    const float* __restrict__ bias, const int* __restrict__ toks,
    float* __restrict__ out)
{
  __shared__ uint4 As[1024];
  __shared__ uint4 Bs[1024];
  __shared__ int tokarr[128];
  __shared__ unsigned long long ballots[2][8];
  __shared__ int perm[128];
  __shared__ int rowsrc[128];

  const int tid  = threadIdx.x;
  const int lane = tid & 63;
  const int wv   = tid >> 6;
  const int wr   = wv >> 1;
  const int wc   = wv & 1;
  const int bid = blockIdx.x;
  const int xcd = bid & 7;
  const int sq  = bid >> 3;
  const int et  = sq & 7;
  const int mt  = (sq >> 3) * 8 + xcd;
  const int m0  = mt * 128;
  const int e0  = et * 128;

  if (tid < 128) tokarr[tid] = toks[tid];
  __syncthreads();
  if (tid < 128) {
    int myt = tokarr[tid];
#pragma unroll
    for (int lg = 0; lg < 8; ++lg) {
      unsigned long long bl = __ballot(myt == lg);
      if (lane == 0) ballots[wv][lg] = bl;
    }
  }
  __syncthreads();
  int lsel = 0, base = 0, csel = 1, boff_sel = 0;
  {
    int cum = 0, boff = 0;
#pragma unroll
    for (int lg = 0; lg < 8; ++lg) {
      int c = __popcll(ballots[0][lg]) + __popcll(ballots[1][lg]);
      int seg = c << 9;
      bool in = (m0 >= cum) && (m0 < cum + seg);
      if (in) { lsel = lg; base = cum; csel = c; boff_sel = boff; }
      cum += seg; boff += c;
    }
  }
  if (tid < 128) {
    int myt = tokarr[tid];
    unsigned long long ltm = (1ull << lane) - 1ull;
    int rank = (wv == 0) ? __popcll(ballots[0][myt] & ltm)
                         : __popcll(ballots[0][myt]) + __popcll(ballots[1][myt] & ltm);
    int boff2 = 0;
#pragma unroll
    for (int lg = 0; lg < 8; ++lg) {
      int c = __popcll(ballots[0][lg]) + __popcll(ballots[1][lg]);
      boff2 += (lg < myt) ? c : 0;
    }
    perm[boff2 + rank] = tid;
  }
  __syncthreads();
  if (tid < 128) {
    int local = m0 - base + tid;
    int s = local / csel;
    int j = local - s * csel;
    rowsrc[tid] = s * BATCH + perm[boff_sel + j];
  }
  __syncthreads();

  int slot_i[4];
  const float* aptr[4];
  const float* bptr[4];
#pragma unroll
  for (int it = 0; it < 4; ++it) {
    int c    = it * 256 + tid;
    int kg   = c & 7;
    int row  = c >> 3;
    int ksub = kg & 3;
    int kk   = kg >> 2;
    int frag = row >> 4;
    slot_i[it] = (kk * 8 + frag) * 64 + ((row & 15) ^ (ksub << 1) ^ kk) + ksub * 16;
    aptr[it] = feat + (size_t)rowsrc[row] * FEAT + kg * 8;
    bptr[it] = Wt + ((size_t)lsel * EMBED + e0 + row) * FEAT + kg * 8;
  }

  f32x4 acc[4][4] = {};
  for (int k0 = 0; k0 < FEAT; k0 += 64) {
    __syncthreads();
#pragma unroll
    for (int it = 0; it < 4; ++it) {
      float4 alo = *(const float4*)(aptr[it] + k0);
      float4 ahi = *(const float4*)(aptr[it] + k0 + 4);
      uint4 av;
      av.x = pk2(alo.x, alo.y); av.y = pk2(alo.z, alo.w);
      av.z = pk2(ahi.x, ahi.y); av.w = pk2(ahi.z, ahi.w);
      As[slot_i[it]] = av;
      float4 blo = *(const float4*)(bptr[it] + k0);
      float4 bhi = *(const float4*)(bptr[it] + k0 + 4);
      uint4 bv;
      bv.x = pk2(blo.x, blo.y); bv.y = pk2(blo.z, blo.w);
      bv.z = pk2(bhi.x, bhi.y); bv.w = pk2(bhi.z, bhi.w);
      Bs[slot_i[it]] = bv;
    }
    __syncthreads();
#pragma unroll
    for (int kk = 0; kk < 2; ++kk) {
      const int ksr = lane >> 4;
      const int sw  = ((lane & 15) ^ (ksr << 1) ^ kk) + ksr * 16;
      bf16x8 af[4], bfr[4];
#pragma unroll
      for (int mi = 0; mi < 4; ++mi)
        af[mi] = ((const bf16x8*)As)[(kk * 8 + wr * 4 + mi) * 64 + sw];
#pragma unroll
      for (int ni = 0; ni < 4; ++ni)
        bfr[ni] = ((const bf16x8*)Bs)[(kk * 8 + wc * 4 + ni) * 64 + sw];
#pragma unroll
      for (int mi = 0; mi < 4; ++mi)
#pragma unroll
        for (int ni = 0; ni < 4; ++ni)
          acc[mi][ni] = __builtin_amdgcn_mfma_f32_16x16x32_bf16(
              af[mi], bfr[ni], acc[mi][ni], 0, 0, 0);
    }
  }

  const int col = lane & 15;
  const int r0  = (lane >> 4) * 4;
  float bvv[4];
#pragma unroll
  for (int ni = 0; ni < 4; ++ni)
    bvv[ni] = bias[lsel * EMBED + e0 + wc * 64 + ni * 16 + col];
#pragma unroll
  for (int mi = 0; mi < 4; ++mi) {
#pragma unroll
    for (int j = 0; j < 4; ++j) {
      const size_t ro = (size_t)rowsrc[wr * 64 + mi * 16 + r0 + j] * EMBED;
#pragma unroll
      for (int ni = 0; ni < 4; ++ni)
        out[ro + e0 + wc * 64 + ni * 16 + col] = acc[mi][ni][j] + bvv[ni];
    }
  }
}

extern "C" void kernel_launch(void* const* d_in, const int* in_sizes, int n_in,
                              void* d_out, int out_size, void* d_ws, size_t ws_size,
                              hipStream_t stream) {
  const float* feat = (const float*)d_in[0];
  const float* W    = (const float*)d_in[1];
  const float* bias = (const float*)d_in[2];
  const int*   toks = (const int*)d_in[3];
  float* out = (float*)d_out;

  const size_t abf_bytes = (size_t)SEQ * BATCH * FEAT * 2;        // 128 MiB
  const size_t wbf_bytes = (size_t)NLANG * EMBED * FEAT * 2;      // 16 MiB

  if (ws_size >= abf_bytes + wbf_bytes) {
    ushort_t* Abf = (ushort_t*)d_ws;
    ushort_t* Wbf = (ushort_t*)((char*)d_ws + abf_bytes);
    convert_permute_kernel<<<3072, 256, 0, stream>>>(feat, W, toks, Abf, Wbf);
    (void)hipFuncSetAttribute((const void*)grouped_gemm_8ph,
                              hipFuncAttributeMaxDynamicSharedMemorySize, 131072);
    const int nblk = (SEQ * BATCH / 256) * (EMBED / 256);         // 1024
    grouped_gemm_8ph<<<nblk, 512, 131072, stream>>>(Abf, Wbf, bias, toks, out);
  } else {
    grouped_proj_fused<<<(SEQ * BATCH / 128) * (EMBED / 128), 256, 0, stream>>>(
        feat, W, bias, toks, out);
  }
}

// Round 6
// 241.548 us; speedup vs baseline: 3.3628x; 1.0794x over previous
//
#include <hip/hip_runtime.h>
#include <hip/hip_bf16.h>

#define SEQ   512
#define BATCH 128
#define FEAT  1024
#define EMBED 1024
#define NLANG 8

typedef __attribute__((ext_vector_type(8))) short bf16x8;
typedef __attribute__((ext_vector_type(4))) float f32x4;
typedef unsigned short ushort_t;

__device__ __forceinline__ unsigned pk2(float a, float b) {
  float2 f; f.x = a; f.y = b;
  __hip_bfloat162 h = __float22bfloat162_rn(f);   // v_cvt_pk_bf16_f32
  union { __hip_bfloat162 h2; unsigned u; } cv;
  cv.h2 = h;
  return cv.u;
}

__device__ __forceinline__ bf16x8 cvt8(f32x4 lo, f32x4 hi) {
  union { bf16x8 v; unsigned u[4]; } q;
  q.u[0] = pk2(lo[0], lo[1]); q.u[1] = pk2(lo[2], lo[3]);
  q.u[2] = pk2(hi[0], hi[1]); q.u[3] = pk2(hi[2], hi[3]);
  return q.v;
}

__device__ __forceinline__ void gld16(const void* g, void* l) {
  __builtin_amdgcn_global_load_lds(
      (const __attribute__((address_space(1))) void*)g,
      (__attribute__((address_space(3))) void*)l, 16, 0, 0);
}

// ---------------- Pass 1 (W only): f32 -> bf16, linear. ~48 MB traffic. -----
__global__ __launch_bounds__(256) void convert_w_kernel(
    const float* __restrict__ Wf, ushort_t* __restrict__ Wbf)
{
  const int n = (NLANG * EMBED * FEAT) / 4;
  for (int c = blockIdx.x * 256 + threadIdx.x; c < n; c += gridDim.x * 256) {
    float4 v = ((const float4*)Wf)[c];
    uint2 o; o.x = pk2(v.x, v.y); o.y = pk2(v.z, v.w);
    *(uint2*)(Wbf + ((size_t)c << 2)) = o;
  }
}

// ---------------- Pass 2: fused grouped GEMM, A gathered+converted in-kernel.
// 256x256 tile, BK=32 granules, ring of 3 LDS bufs (A f32 32 KiB + B bf16
// 16 KiB each = 144 KiB), counted vmcnt(6), 2 phases x 16 MFMA per granule,
// setprio. 512 threads = 8 waves (2M x 4N); per-wave 128x64 via acc[8][4]. ---
__global__ __launch_bounds__(512, 2) void grouped_gemm_fused(
    const float* __restrict__ feat,    // [S*B, F] f32 (original order)
    const ushort_t* __restrict__ Wbf,  // [L, E, F] bf16
    const float* __restrict__ bias,    // [L, E]
    const int*   __restrict__ toks,    // [B]
    float*       __restrict__ out)     // [S*B, E] original order
{
  extern __shared__ char ldsraw[];             // 147456 B dynamic
  float*    Af = (float*)ldsraw;               // 3 bufs x 8192 f32 (32 KiB)
  ushort_t* Bf = (ushort_t*)(ldsraw + 98304);  // 3 bufs x 8192 bf16 (16 KiB)
  __shared__ int tokarr[128];
  __shared__ unsigned long long ballots[2][8];
  __shared__ int perm[128];
  __shared__ int rowsrc[256];

  const int tid = threadIdx.x;
  const int l   = tid & 63;
  const int w   = tid >> 6;
  const int wr  = w >> 2;                    // 0..1 (M half)
  const int wc  = w & 3;                     // 0..3 (N quarter)

  // XCD-chunked bijective swizzle (1024 blocks = 8 XCDs x 128): et-siblings
  // of one mt are adjacent on one XCD -> shared A fetches via that XCD's L2.
  const int bid = blockIdx.x;
  const int L   = (bid & 7) * 128 + (bid >> 3);
  const int et  = L & 3;
  const int mt  = (L >> 7) * 32 + ((L >> 2) & 31);
  const int m0  = mt * 256;
  const int e0  = et * 256;

  // ---- bucket setup (ballot histogram + rank; waves 0,1 vote) ----
  if (tid < 128) tokarr[tid] = toks[tid];
  __syncthreads();
  if (tid < 128) {
    int myt = tokarr[tid];
#pragma unroll
    for (int lg = 0; lg < 8; ++lg) {
      unsigned long long bl = __ballot(myt == lg);
      if (l == 0) ballots[w][lg] = bl;
    }
  }
  __syncthreads();

  int lsel = 0, base = 0, csel = 1, boff_sel = 0;
  {
    int cum = 0, boff = 0;
#pragma unroll
    for (int lg = 0; lg < 8; ++lg) {
      int c = __popcll(ballots[0][lg]) + __popcll(ballots[1][lg]);
      int seg = c << 9;
      bool in = (m0 >= cum) && (m0 < cum + seg);
      if (in) { lsel = lg; base = cum; csel = c; boff_sel = boff; }
      cum += seg; boff += c;
    }
  }

  if (tid < 128) {
    int myt = tokarr[tid];
    unsigned long long ltm = (1ull << l) - 1ull;
    int rank = (w == 0) ? __popcll(ballots[0][myt] & ltm)
                        : __popcll(ballots[0][myt]) + __popcll(ballots[1][myt] & ltm);
    int boff2 = 0;
#pragma unroll
    for (int lg = 0; lg < 8; ++lg) {
      int c = __popcll(ballots[0][lg]) + __popcll(ballots[1][lg]);
      boff2 += (lg < myt) ? c : 0;
    }
    perm[boff2 + rank] = tid;
  }
  __syncthreads();
  if (tid < 256) {
    int local = m0 - base + tid;
    int s = local / csel;
    int j = local - s * csel;
    rowsrc[tid] = s * BATCH + perm[boff_sel + j];
  }
  __syncthreads();

  // ---- A staging: granule = 256 rows x 32 f32 = 32 KiB = 2048 chunks of
  // 16B. chunk c = row*8 + slot; thread owns c = (w*4+i)*64 + l, i=0..3.
  // LDS dest linear; global src slot = slot ^ (row&7) (inverse swizzle,
  // rule #21) gathered from feat row rowsrc[row]. ----
  const float* aSrc[4];
#pragma unroll
  for (int i = 0; i < 4; ++i) {
    const int c    = (w * 4 + i) * 64 + l;
    const int row  = c >> 3;
    const int slot = c & 7;
    aSrc[i] = feat + (size_t)rowsrc[row] * FEAT + ((slot ^ (row & 7)) << 2);
  }
  const int aD0 = w * 1024;              // f32 units within an A buf
  const int aD1 = aD0 + 256;
  const int aD2 = aD0 + 512;
  const int aD3 = aD0 + 768;

  // ---- B staging (R4-verified): granule = 256 rows x 32 bf16 = 16 KiB =
  // 1024 chunks; c = row*4 + cc; src chunk = cc ^ ((row>>1)&3). ----
  const int ca  = w * 128 + l;
  const int rwB = ca >> 2;
  const int ccB = ca & 3;
  const int sB  = (rwB >> 1) & 3;
  const ushort_t* bS0 = Wbf + ((size_t)lsel * EMBED + e0 + rwB) * FEAT + ((ccB ^ sB) * 8);
  const ushort_t* bS1 = bS0 + (size_t)16 * FEAT;
  const int bD0 = (w * 128) * 8;         // ushort units within a B buf
  const int bD1 = (w * 128 + 64) * 8;

  // ---- fragment read offsets ----
  // A (f32): row rA = wr*128 + mf*16 + (l&15); rA&7 == l&7. Two b128 reads at
  // slots (2kc)^(l&7), (2kc+1)^(l&7) -> conflict-free (lanes 0-7 cover all
  // 32 banks, 2-way aliasing free).
  const int kc    = l >> 4;
  const int baseA = (wr * 128 + (l & 15)) * 32;            // f32 units
  const int sl0   = ((2 * kc) ^ (l & 7)) * 4;
  const int sl1   = ((2 * kc + 1) ^ (l & 7)) * 4;
  // B (bf16): as R4.
  const int rB  = wc * 64 + (l & 15);
  const int bRd = rB * 32 + ((kc ^ ((rB >> 1) & 3)) * 8);  // ushort units

  f32x4 acc[8][4] = {};
  bf16x8 af0[4], af1[4], bfq[4];

#define STAGE_A(kt, buf)                                                   \
  do { const int _o = (kt) * 32;                                           \
    gld16(aSrc[0] + _o, Af + (buf) * 8192 + aD0);                          \
    gld16(aSrc[1] + _o, Af + (buf) * 8192 + aD1);                          \
    gld16(aSrc[2] + _o, Af + (buf) * 8192 + aD2);                          \
    gld16(aSrc[3] + _o, Af + (buf) * 8192 + aD3); } while (0)
#define STAGE_B(kt, buf)                                                   \
  do { const int _o = (kt) * 32;                                           \
    gld16(bS0 + _o, Bf + (buf) * 8192 + bD0);                              \
    gld16(bS1 + _o, Bf + (buf) * 8192 + bD1); } while (0)

// Phase 0 of granule g: read+cvt A m-half0, read all B, stage A(g+2),
// MFMA acc[0..3]. rbuf/sbuf are compile-time ring indices (g%3, (g+2)%3).
#define PH0(g, rbuf, sbuf, DOSTAGE)                                        \
  do {                                                                     \
    const float*    Ab_ = Af + (rbuf) * 8192;                              \
    const ushort_t* Bb_ = Bf + (rbuf) * 8192;                              \
    _Pragma("unroll") for (int mf = 0; mf < 4; ++mf) {                     \
      f32x4 lo_ = *(const f32x4*)(Ab_ + baseA + mf * 512 + sl0);           \
      f32x4 hi_ = *(const f32x4*)(Ab_ + baseA + mf * 512 + sl1);           \
      af0[mf] = cvt8(lo_, hi_);                                            \
    }                                                                      \
    _Pragma("unroll") for (int nf = 0; nf < 4; ++nf)                       \
      bfq[nf] = *(const bf16x8*)(Bb_ + bRd + nf * 512);                    \
    if (DOSTAGE) { STAGE_A((g) + 2, sbuf); }                               \
    __builtin_amdgcn_sched_barrier(0);                                     \
    __builtin_amdgcn_s_barrier();                                          \
    asm volatile("s_waitcnt lgkmcnt(0)" ::: "memory");                     \
    __builtin_amdgcn_sched_barrier(0);                                     \
    __builtin_amdgcn_s_setprio(1);                                         \
    _Pragma("unroll") for (int mf = 0; mf < 4; ++mf)                       \
        _Pragma("unroll") for (int nf = 0; nf < 4; ++nf)                   \
            acc[mf][nf] = __builtin_amdgcn_mfma_f32_16x16x32_bf16(         \
                af0[mf], bfq[nf], acc[mf][nf], 0, 0, 0);                   \
    __builtin_amdgcn_s_setprio(0);                                         \
    __builtin_amdgcn_s_barrier();                                          \
  } while (0)

// Phase 1 of granule g: read+cvt A m-half1, stage B(g+2), MFMA acc[4..7],
// counted vmcnt (WAIT) before closing barrier.
#define PH1(g, rbuf, sbuf, DOSTAGE, WAIT)                                  \
  do {                                                                     \
    const float* Ab_ = Af + (rbuf) * 8192;                                 \
    _Pragma("unroll") for (int mf = 0; mf < 4; ++mf) {                     \
      f32x4 lo_ = *(const f32x4*)(Ab_ + baseA + (mf + 4) * 512 + sl0);     \
      f32x4 hi_ = *(const f32x4*)(Ab_ + baseA + (mf + 4) * 512 + sl1);     \
      af1[mf] = cvt8(lo_, hi_);                                            \
    }                                                                      \
    if (DOSTAGE) { STAGE_B((g) + 2, sbuf); }                               \
    __builtin_amdgcn_sched_barrier(0);                                     \
    __builtin_amdgcn_s_barrier();                                          \
    asm volatile("s_waitcnt lgkmcnt(0)" ::: "memory");                     \
    __builtin_amdgcn_sched_barrier(0);                                     \
    __builtin_amdgcn_s_setprio(1);                                         \
    _Pragma("unroll") for (int mf = 0; mf < 4; ++mf)                       \
        _Pragma("unroll") for (int nf = 0; nf < 4; ++nf)                   \
            acc[mf + 4][nf] = __builtin_amdgcn_mfma_f32_16x16x32_bf16(     \
                af1[mf], bfq[nf], acc[mf + 4][nf], 0, 0, 0);               \
    __builtin_amdgcn_s_setprio(0);                                         \
    asm volatile(WAIT ::: "memory");                                       \
    __builtin_amdgcn_s_barrier();                                          \
  } while (0)

  // prologue: stage granules 0,1 (12 loads); vmcnt(6) -> granule 0 resident
  // (in-order retire leaves granule 1's 6 outstanding).
  STAGE_A(0, 0); STAGE_B(0, 0);
  STAGE_A(1, 1); STAGE_B(1, 1);
  asm volatile("s_waitcnt vmcnt(6)" ::: "memory");
  __builtin_amdgcn_s_barrier();
  __builtin_amdgcn_sched_barrier(0);

  // steady state (ring-3): granule g reads buf g%3, stages g+2 into
  // (g+2)%3 == (g-1)%3 (its readers finished at end-of-(g-1) barrier).
  // vmcnt(6) at granule end retires g+1's 6 loads (g+2's 6 remain).
#pragma unroll 1
  for (int gg = 0; gg < 10; ++gg) {
    const int g = gg * 3;
    PH0(g + 0, 0, 2, true);  PH1(g + 0, 0, 2, true, "s_waitcnt vmcnt(6)");
    PH0(g + 1, 1, 0, true);  PH1(g + 1, 1, 0, true, "s_waitcnt vmcnt(6)");
    PH0(g + 2, 2, 1, true);  PH1(g + 2, 2, 1, true, "s_waitcnt vmcnt(6)");
  }
  // tail: granule 30 (buf 0), wait 0 -> granule 31 resident; granule 31 (buf 1).
  PH0(30, 0, 0, false); PH1(30, 0, 0, false, "s_waitcnt vmcnt(0)");
  PH0(31, 1, 0, false); PH1(31, 1, 0, false, "s_nop 0");

#undef PH0
#undef PH1
#undef STAGE_A
#undef STAGE_B

  // ---- epilogue: C/D col = lane&15 (-> e), row = (lane>>4)*4+j (-> m) ----
  const int col = l & 15;
  const int r4  = (l >> 4) * 4;
  float bvv[4];
#pragma unroll
  for (int nf = 0; nf < 4; ++nf)
    bvv[nf] = bias[lsel * EMBED + e0 + wc * 64 + nf * 16 + col];
#pragma unroll
  for (int mf = 0; mf < 8; ++mf) {
#pragma unroll
    for (int j = 0; j < 4; ++j) {
      const size_t ro = (size_t)rowsrc[wr * 128 + mf * 16 + r4 + j] * EMBED;
#pragma unroll
      for (int nf = 0; nf < 4; ++nf)
        out[ro + e0 + wc * 64 + nf * 16 + col] = acc[mf][nf][j] + bvv[nf];
    }
  }
}

// ---------------- Fallback (R2 fused kernel) if ws too small ----------------
__global__ __launch_bounds__(256, 2) void grouped_proj_fused(
    const float* __restrict__ feat, const float* __restrict__ Wt,
    const float* __restrict__ bias, const int* __restrict__ toks,
    float* __restrict__ out)
{
  __shared__ uint4 As[1024];
  __shared__ uint4 Bs[1024];
  __shared__ int tokarr[128];
  __shared__ unsigned long long ballots[2][8];
  __shared__ int perm[128];
  __shared__ int rowsrc[128];

  const int tid  = threadIdx.x;
  const int lane = tid & 63;
  const int wv   = tid >> 6;
  const int wr   = wv >> 1;
  const int wc   = wv & 1;
  const int bid = blockIdx.x;
  const int xcd = bid & 7;
  const int sq  = bid >> 3;
  const int et  = sq & 7;
  const int mt  = (sq >> 3) * 8 + xcd;
  const int m0  = mt * 128;
  const int e0  = et * 128;

  if (tid < 128) tokarr[tid] = toks[tid];
  __syncthreads();
  if (tid < 128) {
    int myt = tokarr[tid];
#pragma unroll
    for (int lg = 0; lg < 8; ++lg) {
      unsigned long long bl = __ballot(myt == lg);
      if (lane == 0) ballots[wv][lg] = bl;
    }
  }
  __syncthreads();
  int lsel = 0, base = 0, csel = 1, boff_sel = 0;
  {
    int cum = 0, boff = 0;
#pragma unroll
    for (int lg = 0; lg < 8; ++lg) {
      int c = __popcll(ballots[0][lg]) + __popcll(ballots[1][lg]);
      int seg = c << 9;
      bool in = (m0 >= cum) && (m0 < cum + seg);
      if (in) { lsel = lg; base = cum; csel = c; boff_sel = boff; }
      cum += seg; boff += c;
    }
  }
  if (tid < 128) {
    int myt = tokarr[tid];
    unsigned long long ltm = (1ull << lane) - 1ull;
    int rank = (wv == 0) ? __popcll(ballots[0][myt] & ltm)
                         : __popcll(ballots[0][myt]) + __popcll(ballots[1][myt] & ltm);
    int boff2 = 0;
#pragma unroll
    for (int lg = 0; lg < 8; ++lg) {
      int c = __popcll(ballots[0][lg]) + __popcll(ballots[1][lg]);
      boff2 += (lg < myt) ? c : 0;
    }
    perm[boff2 + rank] = tid;
  }
  __syncthreads();
  if (tid < 128) {
    int local = m0 - base + tid;
    int s = local / csel;
    int j = local - s * csel;
    rowsrc[tid] = s * BATCH + perm[boff_sel + j];
  }
  __syncthreads();

  int slot_i[4];
  const float* aptr[4];
  const float* bptr[4];
#pragma unroll
  for (int it = 0; it < 4; ++it) {
    int c    = it * 256 + tid;
    int kg   = c & 7;
    int row  = c >> 3;
    int ksub = kg & 3;
    int kk   = kg >> 2;
    int frag = row >> 4;
    slot_i[it] = (kk * 8 + frag) * 64 + ((row & 15) ^ (ksub << 1) ^ kk) + ksub * 16;
    aptr[it] = feat + (size_t)rowsrc[row] * FEAT + kg * 8;
    bptr[it] = Wt + ((size_t)lsel * EMBED + e0 + row) * FEAT + kg * 8;
  }

  f32x4 acc[4][4] = {};
  for (int k0 = 0; k0 < FEAT; k0 += 64) {
    __syncthreads();
#pragma unroll
    for (int it = 0; it < 4; ++it) {
      float4 alo = *(const float4*)(aptr[it] + k0);
      float4 ahi = *(const float4*)(aptr[it] + k0 + 4);
      uint4 av;
      av.x = pk2(alo.x, alo.y); av.y = pk2(alo.z, alo.w);
      av.z = pk2(ahi.x, ahi.y); av.w = pk2(ahi.z, ahi.w);
      As[slot_i[it]] = av;
      float4 blo = *(const float4*)(bptr[it] + k0);
      float4 bhi = *(const float4*)(bptr[it] + k0 + 4);
      uint4 bv;
      bv.x = pk2(blo.x, blo.y); bv.y = pk2(blo.z, blo.w);
      bv.z = pk2(bhi.x, bhi.y); bv.w = pk2(bhi.z, bhi.w);
      Bs[slot_i[it]] = bv;
    }
    __syncthreads();
#pragma unroll
    for (int kk = 0; kk < 2; ++kk) {
      const int ksr = lane >> 4;
      const int sw  = ((lane & 15) ^ (ksr << 1) ^ kk) + ksr * 16;
      bf16x8 af[4], bfr[4];
#pragma unroll
      for (int mi = 0; mi < 4; ++mi)
        af[mi] = ((const bf16x8*)As)[(kk * 8 + wr * 4 + mi) * 64 + sw];
#pragma unroll
      for (int ni = 0; ni < 4; ++ni)
        bfr[ni] = ((const bf16x8*)Bs)[(kk * 8 + wc * 4 + ni) * 64 + sw];
#pragma unroll
      for (int mi = 0; mi < 4; ++mi)
#pragma unroll
        for (int ni = 0; ni < 4; ++ni)
          acc[mi][ni] = __builtin_amdgcn_mfma_f32_16x16x32_bf16(
              af[mi], bfr[ni], acc[mi][ni], 0, 0, 0);
    }
  }

  const int col = lane & 15;
  const int r0  = (lane >> 4) * 4;
  float bvv[4];
#pragma unroll
  for (int ni = 0; ni < 4; ++ni)
    bvv[ni] = bias[lsel * EMBED + e0 + wc * 64 + ni * 16 + col];
#pragma unroll
  for (int mi = 0; mi < 4; ++mi) {
#pragma unroll
    for (int j = 0; j < 4; ++j) {
      const size_t ro = (size_t)rowsrc[wr * 64 + mi * 16 + r0 + j] * EMBED;
#pragma unroll
      for (int ni = 0; ni < 4; ++ni)
        out[ro + e0 + wc * 64 + ni * 16 + col] = acc[mi][ni][j] + bvv[ni];
    }
  }
}

extern "C" void kernel_launch(void* const* d_in, const int* in_sizes, int n_in,
                              void* d_out, int out_size, void* d_ws, size_t ws_size,
                              hipStream_t stream) {
  const float* feat = (const float*)d_in[0];
  const float* W    = (const float*)d_in[1];
  const float* bias = (const float*)d_in[2];
  const int*   toks = (const int*)d_in[3];
  float* out = (float*)d_out;

  const size_t wbf_bytes = (size_t)NLANG * EMBED * FEAT * 2;      // 16 MiB

  if (ws_size >= wbf_bytes) {
    ushort_t* Wbf = (ushort_t*)d_ws;
    convert_w_kernel<<<512, 256, 0, stream>>>(W, Wbf);
    (void)hipFuncSetAttribute((const void*)grouped_gemm_fused,
                              hipFuncAttributeMaxDynamicSharedMemorySize, 147456);
    const int nblk = (SEQ * BATCH / 256) * (EMBED / 256);         // 1024
    grouped_gemm_fused<<<nblk, 512, 147456, stream>>>(feat, Wbf, bias, toks, out);
  } else {
    grouped_proj_fused<<<(SEQ * BATCH / 128) * (EMBED / 128), 256, 0, stream>>>(
        feat, W, bias, toks, out);
  }
}